// Round 6
// baseline (225.234 us; speedup 1.0000x reference)
//
#include <hip/hip_runtime.h>
#include <math.h>

// Problem constants (B=4, T_p=T_f=8, S=256, d=512, heads=8)
#define BB   4
#define SS   256
#define DD   512
#define HH   8
#define HD   64
#define HALF 32
#define TT   32      // total tokens per sequence
#define TV   16      // vp+vf tokens (vary per (b,s))
#define W3   1536    // 3*d
#define MROWS  16448 // 16384 v-rows + 64 unique a-rows
#define MPAD   16512 // 129 * 128

#define VP_BASE 0
#define VF_BASE 4194304      // 4*8*256*512
#define AP_BASE 8388608      // 2*4194304
#define AF_BASE 8404992      // AP_BASE + 4*8*512

#define LN10000_OVER_HALF (9.210340371976184f / 32.0f)

typedef _Float16 h2 __attribute__((ext_vector_type(2)));
typedef _Float16 h4 __attribute__((ext_vector_type(4)));
typedef _Float16 h8 __attribute__((ext_vector_type(8)));
typedef float    f4 __attribute__((ext_vector_type(4)));
typedef float    f16v __attribute__((ext_vector_type(16)));

__device__ __forceinline__ float ropefreq(int i) {
    return __expf(-(float)i * LN10000_OVER_HALF);   // 10000^(-i/32)
}

// async global->LDS, 16 bytes per lane (global_load_lds_dwordx4)
typedef __attribute__((address_space(3))) void*       lds_ptr_t;
typedef const __attribute__((address_space(1))) void* gbl_ptr_t;
__device__ __forceinline__ void async16(const void* g, void* l) {
    __builtin_amdgcn_global_load_lds((gbl_ptr_t)g, (lds_ptr_t)l, 16, 0, 0);
}

// token row r (0..16511) -> source fp32 row pointer (rows >=16448 clamped)
__device__ __forceinline__ const float* row_src(int gr,
        const float* __restrict__ v_p, const float* __restrict__ v_f,
        const float* __restrict__ a_p, const float* __restrict__ a_f) {
    if (gr < 16384) {
        int bs = gr >> 4, t = gr & 15, b = bs >> 8, s = bs & 255;
        return (t < 8) ? v_p + (size_t)((b * 8 + t) * SS + s) * DD
                       : v_f + (size_t)((b * 8 + t - 8) * SS + s) * DD;
    }
    int idx = gr - 16384;
    if (idx >= 64) idx = 0;                 // padding rows: any valid source
    int b = idx >> 4, t2 = idx & 15;
    return (t2 < 8) ? a_p + (size_t)(b * 8 + t2) * DD
                    : a_f + (size_t)(b * 8 + (t2 - 8)) * DD;
}

// ---------------------------------------------------------------------------
// Weight transpose+convert only (token gather is fused into gemm_qkv now).
// 256 blocks: Wqkv -> Wt[n][k] (1536x512), Wp -> Wpt[n][k] (512x512).
// ---------------------------------------------------------------------------
__global__ __launch_bounds__(256)
void conv_w_kernel(const float* __restrict__ Wqkv, const float* __restrict__ Wp,
                   _Float16* __restrict__ Wt, _Float16* __restrict__ Wpt) {
    __shared__ float tile[64 * 65];
    const int tb = blockIdx.x, tid = threadIdx.x;
    const float* src; _Float16* dst; int ld, k0, n0;
    if (tb < 192) {                      // Wqkv: 512(k) x 1536(n), 8x24 tiles
        src = Wqkv; dst = Wt; ld = W3;
        k0 = (tb & 7) * 64; n0 = (tb >> 3) * 64;
    } else {                             // Wp: 512 x 512, 8x8 tiles
        int t2 = tb - 192;
        src = Wp; dst = Wpt; ld = DD;
        k0 = (t2 & 7) * 64; n0 = (t2 >> 3) * 64;
    }
#pragma unroll
    for (int p = 0; p < 16; ++p) {
        int idx = p * 256 + tid, rr = idx >> 6, cc = idx & 63;
        tile[rr * 65 + cc] = src[(size_t)(k0 + rr) * ld + n0 + cc];
    }
    __syncthreads();
#pragma unroll
    for (int p = 0; p < 16; ++p) {
        int idx = p * 256 + tid, rr = idx >> 6, cc = idx & 63;
        dst[(size_t)(n0 + rr) * DD + k0 + cc] = (_Float16)tile[cc * 65 + rr];
    }
}

// ---------------------------------------------------------------------------
// MFMA GEMM 1 (fused token gather): qkv[16512][1536] = tok @ Wqkv.
// A staged straight from fp32 inputs (float4 -> cvt -> ds_write, padded
// stride-40 LDS => ~conflict-free); B via async16. 128x128 tiles, acc 4x4,
// 1-D grid 129*12 tn-fastest. __launch_bounds__(256,3) => 3 blocks/CU.
// ---------------------------------------------------------------------------
__global__ __launch_bounds__(256, 3)
void gemm_qkv_kernel(const float* __restrict__ v_p, const float* __restrict__ v_f,
                     const float* __restrict__ a_p, const float* __restrict__ a_f,
                     const _Float16* __restrict__ Bt, _Float16* __restrict__ C) {
    __shared__ _Float16 As[128 * 40];                 // 10 KB, padded stride 40
    __shared__ __align__(16) _Float16 Bs[128 * 32];   //  8 KB, dense (async16)
    const int tid = threadIdx.x, lane = tid & 63, wave = tid >> 6;
    const int bid = blockIdx.x;
    const int tm = bid / 12, tn = bid % 12;
    const int m_base = (wave >> 1) * 64, n_base = (wave & 1) * 64;
    const int quad = lane >> 4, l16 = lane & 15;

    // Per-thread A-staging assignment: 4 chunks of 4 fp32.
    const float* srcp[4]; int ldsoff[4];
#pragma unroll
    for (int p = 0; p < 4; ++p) {
        int i = p * 256 + tid;                 // [0,1024)
        int r = i >> 3, c = (i & 7) * 4;       // row in tile, col (fp32 units)
        srcp[p] = row_src(tm * 128 + r, v_p, v_f, a_p, a_f) + c;
        ldsoff[p] = r * 40 + c;
    }

    f4 acc[4][4] = {};

    for (int k0 = 0; k0 < 512; k0 += 32) {
        // A: fp32 global -> VGPR (issued first so their waitcnt excludes B)
        float4 av[4];
#pragma unroll
        for (int p = 0; p < 4; ++p) av[p] = *(const float4*)(srcp[p] + k0);
        // B: async16 direct to LDS
#pragma unroll
        for (int rnd = 0; rnd < 2; ++rnd) {
            int i = rnd * 256 + tid;
            int r = i >> 2, c = (i & 3) * 8;
            async16(Bt + (size_t)(tn * 128 + r) * 512 + k0 + c, &Bs[i * 8]);
        }
        // A: convert + LDS write (8 B each)
#pragma unroll
        for (int p = 0; p < 4; ++p) {
            h4 o = { (_Float16)av[p].x, (_Float16)av[p].y,
                     (_Float16)av[p].z, (_Float16)av[p].w };
            *(h4*)&As[ldsoff[p]] = o;
        }
        __syncthreads();

        h8 af[4], bf[4];
#pragma unroll
        for (int mi = 0; mi < 4; ++mi)
            af[mi] = *(const h8*)&As[(m_base + mi * 16 + l16) * 40 + quad * 8];
#pragma unroll
        for (int ni = 0; ni < 4; ++ni)
            bf[ni] = *(const h8*)&Bs[(n_base + ni * 16 + l16) * 32 + quad * 8];
#pragma unroll
        for (int mi = 0; mi < 4; ++mi)
#pragma unroll
            for (int ni = 0; ni < 4; ++ni)
                acc[mi][ni] = __builtin_amdgcn_mfma_f32_16x16x32_f16(
                    af[mi], bf[ni], acc[mi][ni], 0, 0, 0);
        __syncthreads();
    }

    // C/D layout: col = lane&15, row = quad*4 + reg
#pragma unroll
    for (int mi = 0; mi < 4; ++mi)
#pragma unroll
        for (int ni = 0; ni < 4; ++ni) {
            int row = tm * 128 + m_base + mi * 16 + quad * 4;
            int col = tn * 128 + n_base + ni * 16 + l16;
#pragma unroll
            for (int r = 0; r < 4; ++r)
                C[(size_t)(row + r) * W3 + col] = (_Float16)acc[mi][ni][r];
        }
}

// ---------------------------------------------------------------------------
// MFMA attention: grid 2048 = (b,s) x head-group; 4 waves, wave w handles
// head w + 4*hh. Wave-private LDS; no __syncthreads. RoPE in registers
// (pos = row = lane&31). QK^T and PV via v_mfma_f32_32x32x16_f16.
// O held in registers through PV, then staged into the (dead) V tile for
// coalesced 16 B write-back. v-rows -> attnv, a-rows -> attna (dense).
// ---------------------------------------------------------------------------
__global__ __launch_bounds__(256)
void attn5_kernel(const _Float16* __restrict__ qkv, _Float16* __restrict__ attnv,
                  _Float16* __restrict__ attna) {
    __shared__ _Float16 VlA[4][32 * 72];   // per-wave V tile (reused for O)
    __shared__ _Float16 PlA[4][32 * 40];   // per-wave P tile
    const int bid = blockIdx.x;
    const int bs = bid >> 1, hh = bid & 1, b = bs >> 8;
    const int tid = threadIdx.x, wave = tid >> 6, lane = tid & 63;
    const int t = lane & 31, half = lane >> 5;
    _Float16* vl = &VlA[wave][0];
    _Float16* pl = &PlA[wave][0];
    const int h = wave + 4 * hh;

    const size_t row = (t < 16) ? (size_t)(bs * 16 + t)
                                : (size_t)(16384 + b * 16 + (t - 16));
    const _Float16* qp = qkv + row * W3 + h * HD;

    float ccA[8], ssA[8], ccB[8], ssB[8];
#pragma unroll
    for (int j = 0; j < 8; ++j) {
        float aA = (float)t * ropefreq(8 * half + j);
        float aB = (float)t * ropefreq(16 + 8 * half + j);
        __sincosf(aA, &ssA[j], &ccA[j]);
        __sincosf(aB, &ssB[j], &ccB[j]);
    }

    // ---- stage V ----
    h8 v0 = *(const h8*)(qp + 2 * DD + 32 * half);
    h8 v1 = *(const h8*)(qp + 2 * DD + 32 * half + 8);
    h8 v2 = *(const h8*)(qp + 2 * DD + 32 * half + 16);
    h8 v3 = *(const h8*)(qp + 2 * DD + 32 * half + 24);
    *(h8*)&vl[t * 72 + 32 * half +  0] = v0;
    *(h8*)&vl[t * 72 + 32 * half +  8] = v1;
    *(h8*)&vl[t * 72 + 32 * half + 16] = v2;
    *(h8*)&vl[t * 72 + 32 * half + 24] = v3;

    // ---- load Q,K chunks + in-register RoPE ----
    h8 q0 = *(const h8*)(qp + 8 * half);
    h8 q1 = *(const h8*)(qp + 8 * half + 16);
    h8 q2 = *(const h8*)(qp + 8 * half + 32);
    h8 q3 = *(const h8*)(qp + 8 * half + 48);
    h8 k0 = *(const h8*)(qp + DD + 8 * half);
    h8 k1 = *(const h8*)(qp + DD + 8 * half + 16);
    h8 k2 = *(const h8*)(qp + DD + 8 * half + 32);
    h8 k3 = *(const h8*)(qp + DD + 8 * half + 48);

    h8 qf0, qf1, qf2, qf3, kf0, kf1, kf2, kf3;
#pragma unroll
    for (int j = 0; j < 8; ++j) {
        float x1 = (float)q0[j], x2 = (float)q2[j];
        qf0[j] = (_Float16)(0.125f * (x1 * ccA[j] - x2 * ssA[j]));
        qf2[j] = (_Float16)(0.125f * (x2 * ccA[j] + x1 * ssA[j]));
        x1 = (float)q1[j]; x2 = (float)q3[j];
        qf1[j] = (_Float16)(0.125f * (x1 * ccB[j] - x2 * ssB[j]));
        qf3[j] = (_Float16)(0.125f * (x2 * ccB[j] + x1 * ssB[j]));
        x1 = (float)k0[j]; x2 = (float)k2[j];
        kf0[j] = (_Float16)(x1 * ccA[j] - x2 * ssA[j]);
        kf2[j] = (_Float16)(x2 * ccA[j] + x1 * ssA[j]);
        x1 = (float)k1[j]; x2 = (float)k3[j];
        kf1[j] = (_Float16)(x1 * ccB[j] - x2 * ssB[j]);
        kf3[j] = (_Float16)(x2 * ccB[j] + x1 * ssB[j]);
    }

    // ---- scores ----
    f16v s = {};
    s = __builtin_amdgcn_mfma_f32_32x32x16_f16(qf0, kf0, s, 0, 0, 0);
    s = __builtin_amdgcn_mfma_f32_32x32x16_f16(qf1, kf1, s, 0, 0, 0);
    s = __builtin_amdgcn_mfma_f32_32x32x16_f16(qf2, kf2, s, 0, 0, 0);
    s = __builtin_amdgcn_mfma_f32_32x32x16_f16(qf3, kf3, s, 0, 0, 0);

    // ---- softmax per row ----
#pragma unroll
    for (int r = 0; r < 16; ++r) {
        float m = s[r];
#pragma unroll
        for (int mask = 1; mask <= 16; mask <<= 1)
            m = fmaxf(m, __shfl_xor(m, mask));
        float e = __expf(s[r] - m);
        float sm = e;
#pragma unroll
        for (int mask = 1; mask <= 16; mask <<= 1)
            sm += __shfl_xor(sm, mask);
        float p = e / sm;
        int rr = (r & 3) + 8 * (r >> 2) + 4 * half;
        pl[rr * 40 + t] = (_Float16)p;
    }

    // ---- O = P V ----
    f16v o_acc[2];
#pragma unroll
    for (int n0 = 0; n0 < 2; ++n0) {
        f16v o = {};
#pragma unroll
        for (int kk = 0; kk < 2; ++kk) {
            h8 pf = *(const h8*)&pl[t * 40 + kk * 16 + half * 8];
            h8 vf;
#pragma unroll
            for (int jj = 0; jj < 8; ++jj)
                vf[jj] = vl[(kk * 16 + half * 8 + jj) * 72 + n0 * 32 + t];
            o = __builtin_amdgcn_mfma_f32_32x32x16_f16(pf, vf, o, 0, 0, 0);
        }
        o_acc[n0] = o;
    }

    // ---- V tile dead; stage O into it (wave-synchronous) ----
#pragma unroll
    for (int n0 = 0; n0 < 2; ++n0)
#pragma unroll
        for (int r = 0; r < 16; ++r) {
            int i = (r & 3) + 8 * (r >> 2) + 4 * half;
            vl[i * 72 + n0 * 32 + t] = (_Float16)o_acc[n0][r];
        }

    // ---- coalesced write-back ----
#pragma unroll
    for (int rr = 0; rr < 4; ++rr) {
        int i = rr * 8 + (lane >> 3);
        int c = (lane & 7) * 8;
        h8 val = *(const h8*)&vl[i * 72 + c];
        if (rr < 2)
            *(h8*)&attnv[(size_t)(bs * 16 + i) * DD + h * HD + c] = val;
        else
            *(h8*)&attna[((size_t)bs * 16 + (i - 16)) * DD + h * HD + c] = val;
    }
}

// ---------------------------------------------------------------------------
// Merged projection kernel, grid 1088:
//  blocks [0,1024): out_v = attnv @ Wp + bias (128x64 tiles, tn-fastest,
//    acc 2x4 per wave) scattered to vp_o/vf_o.
//  blocks [1024,1088): a-rows: mean over S of attna + fp32 projection.
// ---------------------------------------------------------------------------
__global__ __launch_bounds__(256)
void proj_kernel(const _Float16* __restrict__ A, const _Float16* __restrict__ Bt,
                 const _Float16* __restrict__ attna, const float* __restrict__ Wp,
                 const float* __restrict__ bp, float* __restrict__ out) {
    __shared__ __align__(16) _Float16 As[128 * 32];   // 8 KB
    __shared__ __align__(16) _Float16 Bs[64 * 32];    // 4 KB
    __shared__ float arow[DD];                        // 2 KB
    const int bid = blockIdx.x, tid = threadIdx.x;

    if (bid < 1024) {
        const int lane = tid & 63, wave = tid >> 6;
        const int tm = bid >> 3, tn = bid & 7;
        const int m_base = wave * 32;
        const int quad = lane >> 4, l16 = lane & 15;

        f4 acc[2][4] = {};

        for (int k0 = 0; k0 < 512; k0 += 32) {
#pragma unroll
            for (int rnd = 0; rnd < 2; ++rnd) {       // A: 128x32
                int i = rnd * 256 + tid;
                int r = i >> 2, c = (i & 3) * 8;
                async16(A + (size_t)(tm * 128 + r) * 512 + k0 + c, &As[i * 8]);
            }
            if (tid < 256) {                          // B: 64x32 (1 round, 256 chunks)
                int i = tid;
                int r = i >> 2, c = (i & 3) * 8;
                async16(Bt + (size_t)(tn * 64 + r) * 512 + k0 + c, &Bs[i * 8]);
            }
            __syncthreads();

            h8 af[2], bf[4];
#pragma unroll
            for (int mi = 0; mi < 2; ++mi)
                af[mi] = *(const h8*)&As[(m_base + mi * 16 + l16) * 32 + quad * 8];
#pragma unroll
            for (int ni = 0; ni < 4; ++ni)
                bf[ni] = *(const h8*)&Bs[(ni * 16 + l16) * 32 + quad * 8];
#pragma unroll
            for (int mi = 0; mi < 2; ++mi)
#pragma unroll
                for (int ni = 0; ni < 4; ++ni)
                    acc[mi][ni] = __builtin_amdgcn_mfma_f32_16x16x32_f16(
                        af[mi], bf[ni], acc[mi][ni], 0, 0, 0);
            __syncthreads();
        }

#pragma unroll
        for (int mi = 0; mi < 2; ++mi)
#pragma unroll
            for (int ni = 0; ni < 4; ++ni) {
                int row0 = tm * 128 + m_base + mi * 16 + quad * 4;
                int col  = tn * 64 + ni * 16 + l16;
                float bias = bp[col];
#pragma unroll
                for (int r = 0; r < 4; ++r) {
                    int row = row0 + r;
                    int bsq = row >> 4, t = row & 15;
                    int b = bsq >> 8, s = bsq & 255;
                    size_t off = (t < 8)
                        ? (VP_BASE + (size_t)((b * 8 + t) * SS + s) * DD + col)
                        : (VF_BASE + (size_t)((b * 8 + t - 8) * SS + s) * DD + col);
                    out[off] = acc[mi][ni][r] + bias;
                }
            }
    } else {
        const int r = bid - 1024;            // 0..63
        const int b = r >> 4, t = r & 15;

        float acc0 = 0.f, acc1 = 0.f;
        for (int s = 0; s < SS; ++s) {
            h2 v = *(const h2*)&attna[((size_t)((b * SS + s) * 16 + t)) * DD + tid * 2];
            acc0 += (float)v.x;
            acc1 += (float)v.y;
        }
        arow[tid * 2]     = acc0 * (1.0f / (float)SS);
        arow[tid * 2 + 1] = acc1 * (1.0f / (float)SS);
        __syncthreads();

        for (int jj = 0; jj < 2; ++jj) {
            int j = jj * 256 + tid;
            float acc = bp[j];
            for (int k = 0; k < DD; ++k) acc += arow[k] * Wp[k * DD + j];
            size_t off = (t < 8) ? (AP_BASE + (size_t)(b * 8 + t) * DD + j)
                                 : (AF_BASE + (size_t)(b * 8 + (t - 8)) * DD + j);
            out[off] = acc;
        }
    }
}

// ---------------------------------------------------------------------------
extern "C" void kernel_launch(void* const* d_in, const int* in_sizes, int n_in,
                              void* d_out, int out_size, void* d_ws, size_t ws_size,
                              hipStream_t stream) {
    const float* v_p  = (const float*)d_in[0];
    const float* v_f  = (const float*)d_in[1];
    const float* a_p  = (const float*)d_in[2];
    const float* a_f  = (const float*)d_in[3];
    const float* Wqkv = (const float*)d_in[4];
    const float* Wp   = (const float*)d_in[5];
    const float* bp   = (const float*)d_in[6];
    float* out = (float*)d_out;

    // Workspace layout (~86.3 MB)
    char* w = (char*)d_ws;
    _Float16* qkv   = (_Float16*)w;  w += (size_t)MPAD * W3 * 2;        // 50.7 MB
    _Float16* attnv = (_Float16*)w;  w += (size_t)16384 * DD * 2;       // 16.8 MB
    _Float16* attna = (_Float16*)w;  w += (size_t)16384 * DD * 2;       // 16.8 MB
    _Float16* Wt    = (_Float16*)w;  w += (size_t)W3 * DD * 2;          //  1.6 MB
    _Float16* Wpt   = (_Float16*)w;  w += (size_t)DD * DD * 2;          //  0.5 MB

    conv_w_kernel<<<256, 256, 0, stream>>>(Wqkv, Wp, Wt, Wpt);
    gemm_qkv_kernel<<<129 * 12, 256, 0, stream>>>(v_p, v_f, a_p, a_f, Wt, qkv);
    attn5_kernel<<<2048, 256, 0, stream>>>(qkv, attnv, attna);
    proj_kernel<<<1088, 256, 0, stream>>>(attnv, Wpt, attna, Wp, bp, out);
}

// Round 7
// 217.847 us; speedup vs baseline: 1.0339x; 1.0339x over previous
//
#include <hip/hip_runtime.h>
#include <math.h>

// Problem constants (B=4, T_p=T_f=8, S=256, d=512, heads=8)
#define BB   4
#define SS   256
#define DD   512
#define HH   8
#define HD   64
#define HALF 32
#define TT   32      // total tokens per sequence
#define TV   16      // vp+vf tokens (vary per (b,s))
#define W3   1536    // 3*d
#define MROWS  16448 // 16384 v-rows + 64 unique a-rows
#define MPAD   16512 // 129 * 128

#define VP_BASE 0
#define VF_BASE 4194304      // 4*8*256*512
#define AP_BASE 8388608      // 2*4194304
#define AF_BASE 8404992      // AP_BASE + 4*8*512

#define LN10000_OVER_HALF (9.210340371976184f / 32.0f)

typedef _Float16 h2 __attribute__((ext_vector_type(2)));
typedef _Float16 h4 __attribute__((ext_vector_type(4)));
typedef _Float16 h8 __attribute__((ext_vector_type(8)));
typedef float    f4 __attribute__((ext_vector_type(4)));
typedef float    f16v __attribute__((ext_vector_type(16)));

__device__ __forceinline__ float ropefreq(int i) {
    return __expf(-(float)i * LN10000_OVER_HALF);   // 10000^(-i/32)
}

// async global->LDS, 16 bytes per lane (global_load_lds_dwordx4)
typedef __attribute__((address_space(3))) void*       lds_ptr_t;
typedef const __attribute__((address_space(1))) void* gbl_ptr_t;
__device__ __forceinline__ void async16(const void* g, void* l) {
    __builtin_amdgcn_global_load_lds((gbl_ptr_t)g, (lds_ptr_t)l, 16, 0, 0);
}

// ---------------------------------------------------------------------------
// Fused prep kernel (round-5 version restored).
// Blocks [0, 8224): gather tokens into fp16 tok[16512][512]
//   rows 0..16383: v-tokens (bs=r/16, t=r%16); rows 16384..16447: a-tokens.
// Blocks [8224, 8480): 64x64 LDS-tile transpose+convert Wqkv->Wt, Wp->Wpt.
// ---------------------------------------------------------------------------
__global__ __launch_bounds__(256)
void conv_kernel(const float* __restrict__ v_p, const float* __restrict__ v_f,
                 const float* __restrict__ a_p, const float* __restrict__ a_f,
                 const float* __restrict__ Wqkv, const float* __restrict__ Wp,
                 _Float16* __restrict__ tok, _Float16* __restrict__ Wt,
                 _Float16* __restrict__ Wpt) {
    __shared__ float tile[64 * 65];
    const int bid = blockIdx.x, tid = threadIdx.x;
    if (bid < 8224) {
        int id = bid * 256 + tid;
        int e  = id * 4;
        int r  = e >> 9, c = e & 511;
        const float* src;
        if (r < 16384) {
            int bs = r >> 4, t = r & 15, b = bs >> 8, s = bs & 255;
            src = (t < 8) ? v_p + (size_t)((b * 8 + t) * SS + s) * DD
                          : v_f + (size_t)((b * 8 + t - 8) * SS + s) * DD;
        } else {
            int idx = r - 16384, b = idx >> 4, t2 = idx & 15;
            src = (t2 < 8) ? a_p + (size_t)(b * 8 + t2) * DD
                           : a_f + (size_t)(b * 8 + (t2 - 8)) * DD;
        }
        float4 v = *(const float4*)(src + c);
        h4 o = { (_Float16)v.x, (_Float16)v.y, (_Float16)v.z, (_Float16)v.w };
        *(h4*)(tok + (size_t)r * DD + c) = o;
    } else {
        int tb = bid - 8224;                 // 0..255
        const float* src; _Float16* dst; int ld, k0, n0;
        if (tb < 192) {                      // Wqkv: 512(k) x 1536(n), 8x24 tiles
            src = Wqkv; dst = Wt; ld = W3;
            k0 = (tb & 7) * 64; n0 = (tb >> 3) * 64;
        } else {                             // Wp: 512 x 512, 8x8 tiles
            int t2 = tb - 192;
            src = Wp; dst = Wpt; ld = DD;
            k0 = (t2 & 7) * 64; n0 = (t2 >> 3) * 64;
        }
#pragma unroll
        for (int p = 0; p < 16; ++p) {
            int idx = p * 256 + tid, rr = idx >> 6, cc = idx & 63;
            tile[rr * 65 + cc] = src[(size_t)(k0 + rr) * ld + n0 + cc];
        }
        __syncthreads();
#pragma unroll
        for (int p = 0; p < 16; ++p) {
            int idx = p * 256 + tid, rr = idx >> 6, cc = idx & 63;
            dst[(size_t)(n0 + rr) * DD + k0 + cc] = (_Float16)tile[cc * 65 + rr];
        }
    }
}

// ---------------------------------------------------------------------------
// MFMA GEMM 1: qkv[16512][1536] = tok[16512][512] @ Wqkv (fp16 in/out).
// 128x128 tiles, BK=64 with XOR-swizzled LDS:
//   LDS linear chunk ci = (row r)*8 + slot sl holds global k-chunk
//   c = sl ^ (r&7) of row r  =>  async16 dest stays linear (wave-uniform
//   base + lane*16), while frag ds_read_b128 hits 8 distinct bank-quads
//   (2 lanes each = 2-way = free, m136).
// 1-D grid 129*12 = 1548, tn-fastest; __launch_bounds__(256,3) -> 3 blk/CU
// (768 resident, 2.016 dispatch rounds).
// ---------------------------------------------------------------------------
__global__ __launch_bounds__(256, 3)
void gemm_qkv_kernel(const _Float16* __restrict__ A, const _Float16* __restrict__ Bt,
                     _Float16* __restrict__ C) {
    __shared__ __align__(16) _Float16 As[128 * 64];   // 16 KB
    __shared__ __align__(16) _Float16 Bs[128 * 64];   // 16 KB
    const int tid = threadIdx.x, lane = tid & 63, wave = tid >> 6;
    const int bid = blockIdx.x;
    const int tm = bid / 12, tn = bid % 12;
    const int m_base = (wave >> 1) * 64, n_base = (wave & 1) * 64;
    const int quad = lane >> 4, l16 = lane & 15;

    f4 acc[4][4] = {};

    // staging assignment: 4 chunks each for A and B per thread
    int srow[4], soff[4];
#pragma unroll
    for (int p = 0; p < 4; ++p) {
        int ci = p * 256 + tid;            // [0,1024): r = ci>>3, sl = ci&7
        int r = ci >> 3, sl = ci & 7;
        srow[p] = r;
        soff[p] = (sl ^ (r & 7)) * 8;      // swizzled source k-offset
    }

    for (int k0 = 0; k0 < 512; k0 += 64) {
#pragma unroll
        for (int p = 0; p < 4; ++p) {
            int ci = p * 256 + tid;
            async16(A  + (size_t)(tm * 128 + srow[p]) * 512 + k0 + soff[p],
                    &As[ci * 8]);
            async16(Bt + (size_t)(tn * 128 + srow[p]) * 512 + k0 + soff[p],
                    &Bs[ci * 8]);
        }
        __syncthreads();

#pragma unroll
        for (int kk = 0; kk < 2; ++kk) {
            h8 af[4], bf[4];
#pragma unroll
            for (int mi = 0; mi < 4; ++mi) {
                int m = m_base + mi * 16 + l16;
                int sl = (kk * 4 + quad) ^ (m & 7);
                af[mi] = *(const h8*)&As[m * 64 + sl * 8];
            }
#pragma unroll
            for (int ni = 0; ni < 4; ++ni) {
                int n = n_base + ni * 16 + l16;
                int sl = (kk * 4 + quad) ^ (n & 7);
                bf[ni] = *(const h8*)&Bs[n * 64 + sl * 8];
            }
#pragma unroll
            for (int mi = 0; mi < 4; ++mi)
#pragma unroll
                for (int ni = 0; ni < 4; ++ni)
                    acc[mi][ni] = __builtin_amdgcn_mfma_f32_16x16x32_f16(
                        af[mi], bf[ni], acc[mi][ni], 0, 0, 0);
        }
        __syncthreads();
    }

    // C/D layout: col = lane&15, row = quad*4 + reg
#pragma unroll
    for (int mi = 0; mi < 4; ++mi)
#pragma unroll
        for (int ni = 0; ni < 4; ++ni) {
            int row = tm * 128 + m_base + mi * 16 + quad * 4;
            int col = tn * 128 + n_base + ni * 16 + l16;
#pragma unroll
            for (int r = 0; r < 4; ++r)
                C[(size_t)(row + r) * W3 + col] = (_Float16)acc[mi][ni][r];
        }
}

// ---------------------------------------------------------------------------
// MFMA attention: grid 2048 = (b,s) x head-group; 4 waves, wave w handles
// head w + 4*hh. Wave-private LDS; no __syncthreads. RoPE in registers
// (pos = row = lane&31). QK^T and PV via v_mfma_f32_32x32x16_f16.
// O held in registers through PV, then staged into the (dead) V tile for
// coalesced 16 B write-back. v-rows -> attnv, a-rows -> attna (dense).
// ---------------------------------------------------------------------------
__global__ __launch_bounds__(256)
void attn5_kernel(const _Float16* __restrict__ qkv, _Float16* __restrict__ attnv,
                  _Float16* __restrict__ attna) {
    __shared__ _Float16 VlA[4][32 * 72];   // per-wave V tile (reused for O)
    __shared__ _Float16 PlA[4][32 * 40];   // per-wave P tile
    const int bid = blockIdx.x;
    const int bs = bid >> 1, hh = bid & 1, b = bs >> 8;
    const int tid = threadIdx.x, wave = tid >> 6, lane = tid & 63;
    const int t = lane & 31, half = lane >> 5;
    _Float16* vl = &VlA[wave][0];
    _Float16* pl = &PlA[wave][0];
    const int h = wave + 4 * hh;

    const size_t row = (t < 16) ? (size_t)(bs * 16 + t)
                                : (size_t)(16384 + b * 16 + (t - 16));
    const _Float16* qp = qkv + row * W3 + h * HD;

    float ccA[8], ssA[8], ccB[8], ssB[8];
#pragma unroll
    for (int j = 0; j < 8; ++j) {
        float aA = (float)t * ropefreq(8 * half + j);
        float aB = (float)t * ropefreq(16 + 8 * half + j);
        __sincosf(aA, &ssA[j], &ccA[j]);
        __sincosf(aB, &ssB[j], &ccB[j]);
    }

    // ---- stage V ----
    h8 v0 = *(const h8*)(qp + 2 * DD + 32 * half);
    h8 v1 = *(const h8*)(qp + 2 * DD + 32 * half + 8);
    h8 v2 = *(const h8*)(qp + 2 * DD + 32 * half + 16);
    h8 v3 = *(const h8*)(qp + 2 * DD + 32 * half + 24);
    *(h8*)&vl[t * 72 + 32 * half +  0] = v0;
    *(h8*)&vl[t * 72 + 32 * half +  8] = v1;
    *(h8*)&vl[t * 72 + 32 * half + 16] = v2;
    *(h8*)&vl[t * 72 + 32 * half + 24] = v3;

    // ---- load Q,K chunks + in-register RoPE ----
    h8 q0 = *(const h8*)(qp + 8 * half);
    h8 q1 = *(const h8*)(qp + 8 * half + 16);
    h8 q2 = *(const h8*)(qp + 8 * half + 32);
    h8 q3 = *(const h8*)(qp + 8 * half + 48);
    h8 k0 = *(const h8*)(qp + DD + 8 * half);
    h8 k1 = *(const h8*)(qp + DD + 8 * half + 16);
    h8 k2 = *(const h8*)(qp + DD + 8 * half + 32);
    h8 k3 = *(const h8*)(qp + DD + 8 * half + 48);

    h8 qf0, qf1, qf2, qf3, kf0, kf1, kf2, kf3;
#pragma unroll
    for (int j = 0; j < 8; ++j) {
        float x1 = (float)q0[j], x2 = (float)q2[j];
        qf0[j] = (_Float16)(0.125f * (x1 * ccA[j] - x2 * ssA[j]));
        qf2[j] = (_Float16)(0.125f * (x2 * ccA[j] + x1 * ssA[j]));
        x1 = (float)q1[j]; x2 = (float)q3[j];
        qf1[j] = (_Float16)(0.125f * (x1 * ccB[j] - x2 * ssB[j]));
        qf3[j] = (_Float16)(0.125f * (x2 * ccB[j] + x1 * ssB[j]));
        x1 = (float)k0[j]; x2 = (float)k2[j];
        kf0[j] = (_Float16)(x1 * ccA[j] - x2 * ssA[j]);
        kf2[j] = (_Float16)(x2 * ccA[j] + x1 * ssA[j]);
        x1 = (float)k1[j]; x2 = (float)k3[j];
        kf1[j] = (_Float16)(x1 * ccB[j] - x2 * ssB[j]);
        kf3[j] = (_Float16)(x2 * ccB[j] + x1 * ssB[j]);
    }

    // ---- scores ----
    f16v s = {};
    s = __builtin_amdgcn_mfma_f32_32x32x16_f16(qf0, kf0, s, 0, 0, 0);
    s = __builtin_amdgcn_mfma_f32_32x32x16_f16(qf1, kf1, s, 0, 0, 0);
    s = __builtin_amdgcn_mfma_f32_32x32x16_f16(qf2, kf2, s, 0, 0, 0);
    s = __builtin_amdgcn_mfma_f32_32x32x16_f16(qf3, kf3, s, 0, 0, 0);

    // ---- softmax per row ----
#pragma unroll
    for (int r = 0; r < 16; ++r) {
        float m = s[r];
#pragma unroll
        for (int mask = 1; mask <= 16; mask <<= 1)
            m = fmaxf(m, __shfl_xor(m, mask));
        float e = __expf(s[r] - m);
        float sm = e;
#pragma unroll
        for (int mask = 1; mask <= 16; mask <<= 1)
            sm += __shfl_xor(sm, mask);
        float p = e / sm;
        int rr = (r & 3) + 8 * (r >> 2) + 4 * half;
        pl[rr * 40 + t] = (_Float16)p;
    }

    // ---- O = P V ----
    f16v o_acc[2];
#pragma unroll
    for (int n0 = 0; n0 < 2; ++n0) {
        f16v o = {};
#pragma unroll
        for (int kk = 0; kk < 2; ++kk) {
            h8 pf = *(const h8*)&pl[t * 40 + kk * 16 + half * 8];
            h8 vf;
#pragma unroll
            for (int jj = 0; jj < 8; ++jj)
                vf[jj] = vl[(kk * 16 + half * 8 + jj) * 72 + n0 * 32 + t];
            o = __builtin_amdgcn_mfma_f32_32x32x16_f16(pf, vf, o, 0, 0, 0);
        }
        o_acc[n0] = o;
    }

    // ---- V tile dead; stage O into it (wave-synchronous) ----
#pragma unroll
    for (int n0 = 0; n0 < 2; ++n0)
#pragma unroll
        for (int r = 0; r < 16; ++r) {
            int i = (r & 3) + 8 * (r >> 2) + 4 * half;
            vl[i * 72 + n0 * 32 + t] = (_Float16)o_acc[n0][r];
        }

    // ---- coalesced write-back ----
#pragma unroll
    for (int rr = 0; rr < 4; ++rr) {
        int i = rr * 8 + (lane >> 3);
        int c = (lane & 7) * 8;
        h8 val = *(const h8*)&vl[i * 72 + c];
        if (rr < 2)
            *(h8*)&attnv[(size_t)(bs * 16 + i) * DD + h * HD + c] = val;
        else
            *(h8*)&attna[((size_t)bs * 16 + (i - 16)) * DD + h * HD + c] = val;
    }
}

// ---------------------------------------------------------------------------
// Merged projection kernel, grid 1088:
//  blocks [0,1024): out_v = attnv @ Wp + bias (128x64 tiles, tn-fastest,
//    acc 2x4 per wave) scattered to vp_o/vf_o.
//  blocks [1024,1088): a-rows: mean over S of attna + fp32 projection.
// ---------------------------------------------------------------------------
__global__ __launch_bounds__(256)
void proj_kernel(const _Float16* __restrict__ A, const _Float16* __restrict__ Bt,
                 const _Float16* __restrict__ attna, const float* __restrict__ Wp,
                 const float* __restrict__ bp, float* __restrict__ out) {
    __shared__ __align__(16) _Float16 As[128 * 32];   // 8 KB
    __shared__ __align__(16) _Float16 Bs[64 * 32];    // 4 KB
    __shared__ float arow[DD];                        // 2 KB
    const int bid = blockIdx.x, tid = threadIdx.x;

    if (bid < 1024) {
        const int lane = tid & 63, wave = tid >> 6;
        const int tm = bid >> 3, tn = bid & 7;
        const int m_base = wave * 32;
        const int quad = lane >> 4, l16 = lane & 15;

        f4 acc[2][4] = {};

        for (int k0 = 0; k0 < 512; k0 += 32) {
#pragma unroll
            for (int rnd = 0; rnd < 2; ++rnd) {       // A: 128x32
                int i = rnd * 256 + tid;
                int r = i >> 2, c = (i & 3) * 8;
                async16(A + (size_t)(tm * 128 + r) * 512 + k0 + c, &As[i * 8]);
            }
            {                                         // B: 64x32
                int i = tid;
                int r = i >> 2, c = (i & 3) * 8;
                async16(Bt + (size_t)(tn * 64 + r) * 512 + k0 + c, &Bs[i * 8]);
            }
            __syncthreads();

            h8 af[2], bf[4];
#pragma unroll
            for (int mi = 0; mi < 2; ++mi)
                af[mi] = *(const h8*)&As[(m_base + mi * 16 + l16) * 32 + quad * 8];
#pragma unroll
            for (int ni = 0; ni < 4; ++ni)
                bf[ni] = *(const h8*)&Bs[(ni * 16 + l16) * 32 + quad * 8];
#pragma unroll
            for (int mi = 0; mi < 2; ++mi)
#pragma unroll
                for (int ni = 0; ni < 4; ++ni)
                    acc[mi][ni] = __builtin_amdgcn_mfma_f32_16x16x32_f16(
                        af[mi], bf[ni], acc[mi][ni], 0, 0, 0);
            __syncthreads();
        }

#pragma unroll
        for (int mi = 0; mi < 2; ++mi)
#pragma unroll
            for (int ni = 0; ni < 4; ++ni) {
                int row0 = tm * 128 + m_base + mi * 16 + quad * 4;
                int col  = tn * 64 + ni * 16 + l16;
                float bias = bp[col];
#pragma unroll
                for (int r = 0; r < 4; ++r) {
                    int row = row0 + r;
                    int bsq = row >> 4, t = row & 15;
                    int b = bsq >> 8, s = bsq & 255;
                    size_t off = (t < 8)
                        ? (VP_BASE + (size_t)((b * 8 + t) * SS + s) * DD + col)
                        : (VF_BASE + (size_t)((b * 8 + t - 8) * SS + s) * DD + col);
                    out[off] = acc[mi][ni][r] + bias;
                }
            }
    } else {
        const int r = bid - 1024;            // 0..63
        const int b = r >> 4, t = r & 15;

        float acc0 = 0.f, acc1 = 0.f;
        for (int s = 0; s < SS; ++s) {
            h2 v = *(const h2*)&attna[((size_t)((b * SS + s) * 16 + t)) * DD + tid * 2];
            acc0 += (float)v.x;
            acc1 += (float)v.y;
        }
        arow[tid * 2]     = acc0 * (1.0f / (float)SS);
        arow[tid * 2 + 1] = acc1 * (1.0f / (float)SS);
        __syncthreads();

        for (int jj = 0; jj < 2; ++jj) {
            int j = jj * 256 + tid;
            float acc = bp[j];
            for (int k = 0; k < DD; ++k) acc += arow[k] * Wp[k * DD + j];
            size_t off = (t < 8) ? (AP_BASE + (size_t)(b * 8 + t) * DD + j)
                                 : (AF_BASE + (size_t)(b * 8 + (t - 8)) * DD + j);
            out[off] = acc;
        }
    }
}

// ---------------------------------------------------------------------------
extern "C" void kernel_launch(void* const* d_in, const int* in_sizes, int n_in,
                              void* d_out, int out_size, void* d_ws, size_t ws_size,
                              hipStream_t stream) {
    const float* v_p  = (const float*)d_in[0];
    const float* v_f  = (const float*)d_in[1];
    const float* a_p  = (const float*)d_in[2];
    const float* a_f  = (const float*)d_in[3];
    const float* Wqkv = (const float*)d_in[4];
    const float* Wp   = (const float*)d_in[5];
    const float* bp   = (const float*)d_in[6];
    float* out = (float*)d_out;

    // Workspace layout (~86.6 MB). attna ALIASES tok: tok is dead after
    // gemm_qkv_kernel; attna is written only in attn5_kernel (later on stream).
    char* w = (char*)d_ws;
    _Float16* tok   = (_Float16*)w;  w += (size_t)MPAD * DD * 2;    // 16.9 MB
    _Float16* qkv   = (_Float16*)w;  w += (size_t)MPAD * W3 * 2;    // 50.7 MB
    _Float16* attnv = (_Float16*)w;  w += (size_t)16384 * DD * 2;   // 16.8 MB
    _Float16* Wt    = (_Float16*)w;  w += (size_t)W3 * DD * 2;      //  1.6 MB
    _Float16* Wpt   = (_Float16*)w;  w += (size_t)DD * DD * 2;      //  0.5 MB
    _Float16* attna = tok;                                          // alias

    conv_kernel<<<8480, 256, 0, stream>>>(v_p, v_f, a_p, a_f, Wqkv, Wp,
                                          tok, Wt, Wpt);
    gemm_qkv_kernel<<<129 * 12, 256, 0, stream>>>(tok, Wt, qkv);
    attn5_kernel<<<2048, 256, 0, stream>>>(qkv, attnv, attna);
    proj_kernel<<<1088, 256, 0, stream>>>(attnv, Wpt, attna, Wp, bp, out);
}

// Round 8
// 192.789 us; speedup vs baseline: 1.1683x; 1.1300x over previous
//
#include <hip/hip_runtime.h>
#include <math.h>

// Problem constants (B=4, T_p=T_f=8, S=256, d=512, heads=8)
#define BB   4
#define SS   256
#define DD   512
#define HH   8
#define HD   64
#define HALF 32
#define TT   32      // total tokens per sequence
#define TV   16      // vp+vf tokens (vary per (b,s))
#define W3   1536    // 3*d
#define MROWS  16448 // 16384 v-rows + 64 unique a-rows
#define MPAD   16512 // 129 * 128

#define VP_BASE 0
#define VF_BASE 4194304      // 4*8*256*512
#define AP_BASE 8388608      // 2*4194304
#define AF_BASE 8404992      // AP_BASE + 4*8*512

#define LN10000_OVER_HALF (9.210340371976184f / 32.0f)

typedef _Float16 h2 __attribute__((ext_vector_type(2)));
typedef _Float16 h4 __attribute__((ext_vector_type(4)));
typedef _Float16 h8 __attribute__((ext_vector_type(8)));
typedef float    f4 __attribute__((ext_vector_type(4)));
typedef float    f16v __attribute__((ext_vector_type(16)));

__device__ __forceinline__ float ropefreq(int i) {
    return __expf(-(float)i * LN10000_OVER_HALF);   // 10000^(-i/32)
}

// async global->LDS, 16 bytes per lane (global_load_lds_dwordx4)
typedef __attribute__((address_space(3))) void*       lds_ptr_t;
typedef const __attribute__((address_space(1))) void* gbl_ptr_t;
__device__ __forceinline__ void async16(const void* g, void* l) {
    __builtin_amdgcn_global_load_lds((gbl_ptr_t)g, (lds_ptr_t)l, 16, 0, 0);
}

// ---------------------------------------------------------------------------
// Fused prep kernel.
// Blocks [0, 8224): gather tokens into fp16 tok[16512][512]
//   rows 0..16383: v-tokens (bs=r/16, t=r%16); rows 16384..16447: a-tokens.
// Blocks [8224, 8480): 64x64 LDS-tile transpose+convert Wqkv->Wt, Wp->Wpt.
// ---------------------------------------------------------------------------
__global__ __launch_bounds__(256)
void conv_kernel(const float* __restrict__ v_p, const float* __restrict__ v_f,
                 const float* __restrict__ a_p, const float* __restrict__ a_f,
                 const float* __restrict__ Wqkv, const float* __restrict__ Wp,
                 _Float16* __restrict__ tok, _Float16* __restrict__ Wt,
                 _Float16* __restrict__ Wpt) {
    __shared__ float tile[64 * 65];
    const int bid = blockIdx.x, tid = threadIdx.x;
    if (bid < 8224) {
        int id = bid * 256 + tid;
        int e  = id * 4;
        int r  = e >> 9, c = e & 511;
        const float* src;
        if (r < 16384) {
            int bs = r >> 4, t = r & 15, b = bs >> 8, s = bs & 255;
            src = (t < 8) ? v_p + (size_t)((b * 8 + t) * SS + s) * DD
                          : v_f + (size_t)((b * 8 + t - 8) * SS + s) * DD;
        } else {
            int idx = r - 16384, b = idx >> 4, t2 = idx & 15;
            src = (t2 < 8) ? a_p + (size_t)(b * 8 + t2) * DD
                           : a_f + (size_t)(b * 8 + (t2 - 8)) * DD;
        }
        float4 v = *(const float4*)(src + c);
        h4 o = { (_Float16)v.x, (_Float16)v.y, (_Float16)v.z, (_Float16)v.w };
        *(h4*)(tok + (size_t)r * DD + c) = o;
    } else {
        int tb = bid - 8224;                 // 0..255
        const float* src; _Float16* dst; int ld, k0, n0;
        if (tb < 192) {                      // Wqkv: 512(k) x 1536(n), 8x24 tiles
            src = Wqkv; dst = Wt; ld = W3;
            k0 = (tb & 7) * 64; n0 = (tb >> 3) * 64;
        } else {                             // Wp: 512 x 512, 8x8 tiles
            int t2 = tb - 192;
            src = Wp; dst = Wpt; ld = DD;
            k0 = (t2 & 7) * 64; n0 = (t2 >> 3) * 64;
        }
#pragma unroll
        for (int p = 0; p < 16; ++p) {
            int idx = p * 256 + tid, rr = idx >> 6, cc = idx & 63;
            tile[rr * 65 + cc] = src[(size_t)(k0 + rr) * ld + n0 + cc];
        }
        __syncthreads();
#pragma unroll
        for (int p = 0; p < 16; ++p) {
            int idx = p * 256 + tid, rr = idx >> 6, cc = idx & 63;
            dst[(size_t)(n0 + rr) * DD + k0 + cc] = (_Float16)tile[cc * 65 + rr];
        }
    }
}

// ---------------------------------------------------------------------------
// MFMA GEMM 1: qkv[16512][1536] = tok[16512][512] @ Wqkv (fp16 in/out).
// 128x128 tiles, BK=64, XOR-swizzled LDS (async16 dest linear, frag reads
// 2-way = free). 1-D grid 129*12, tn-fastest; 3 blk/CU.
// ---------------------------------------------------------------------------
__global__ __launch_bounds__(256, 3)
void gemm_qkv_kernel(const _Float16* __restrict__ A, const _Float16* __restrict__ Bt,
                     _Float16* __restrict__ C) {
    __shared__ __align__(16) _Float16 As[128 * 64];   // 16 KB
    __shared__ __align__(16) _Float16 Bs[128 * 64];   // 16 KB
    const int tid = threadIdx.x, lane = tid & 63, wave = tid >> 6;
    const int bid = blockIdx.x;
    const int tm = bid / 12, tn = bid % 12;
    const int m_base = (wave >> 1) * 64, n_base = (wave & 1) * 64;
    const int quad = lane >> 4, l16 = lane & 15;

    f4 acc[4][4] = {};

    int srow[4], soff[4];
#pragma unroll
    for (int p = 0; p < 4; ++p) {
        int ci = p * 256 + tid;            // [0,1024): r = ci>>3, sl = ci&7
        int r = ci >> 3, sl = ci & 7;
        srow[p] = r;
        soff[p] = (sl ^ (r & 7)) * 8;      // swizzled source k-offset
    }

    for (int k0 = 0; k0 < 512; k0 += 64) {
#pragma unroll
        for (int p = 0; p < 4; ++p) {
            int ci = p * 256 + tid;
            async16(A  + (size_t)(tm * 128 + srow[p]) * 512 + k0 + soff[p],
                    &As[ci * 8]);
            async16(Bt + (size_t)(tn * 128 + srow[p]) * 512 + k0 + soff[p],
                    &Bs[ci * 8]);
        }
        __syncthreads();

#pragma unroll
        for (int kk = 0; kk < 2; ++kk) {
            h8 af[4], bf[4];
#pragma unroll
            for (int mi = 0; mi < 4; ++mi) {
                int m = m_base + mi * 16 + l16;
                int sl = (kk * 4 + quad) ^ (m & 7);
                af[mi] = *(const h8*)&As[m * 64 + sl * 8];
            }
#pragma unroll
            for (int ni = 0; ni < 4; ++ni) {
                int n = n_base + ni * 16 + l16;
                int sl = (kk * 4 + quad) ^ (n & 7);
                bf[ni] = *(const h8*)&Bs[n * 64 + sl * 8];
            }
#pragma unroll
            for (int mi = 0; mi < 4; ++mi)
#pragma unroll
                for (int ni = 0; ni < 4; ++ni)
                    acc[mi][ni] = __builtin_amdgcn_mfma_f32_16x16x32_f16(
                        af[mi], bf[ni], acc[mi][ni], 0, 0, 0);
        }
        __syncthreads();
    }

#pragma unroll
    for (int mi = 0; mi < 4; ++mi)
#pragma unroll
        for (int ni = 0; ni < 4; ++ni) {
            int row = tm * 128 + m_base + mi * 16 + quad * 4;
            int col = tn * 128 + n_base + ni * 16 + l16;
#pragma unroll
            for (int r = 0; r < 4; ++r)
                C[(size_t)(row + r) * W3 + col] = (_Float16)acc[mi][ni][r];
        }
}

// ---------------------------------------------------------------------------
// MFMA attention: grid 2048 = (b,s) x head-group; 4 waves, wave w = head
// w + 4*hh. Wave-private LDS; no __syncthreads. RoPE in registers.
// v-rows -> attnv[bs*16+t][c];  a-rows -> attna[(b*16+t)*256+s][c]
// (s-contiguous per (b,t) so the mean reduction reads contiguous memory).
// ---------------------------------------------------------------------------
__global__ __launch_bounds__(256)
void attn5_kernel(const _Float16* __restrict__ qkv, _Float16* __restrict__ attnv,
                  _Float16* __restrict__ attna) {
    __shared__ _Float16 VlA[4][32 * 72];   // per-wave V tile (reused for O)
    __shared__ _Float16 PlA[4][32 * 40];   // per-wave P tile
    const int bid = blockIdx.x;
    const int bs = bid >> 1, hh = bid & 1, b = bs >> 8, s = bs & 255;
    const int tid = threadIdx.x, wave = tid >> 6, lane = tid & 63;
    const int t = lane & 31, half = lane >> 5;
    _Float16* vl = &VlA[wave][0];
    _Float16* pl = &PlA[wave][0];
    const int h = wave + 4 * hh;

    const size_t row = (t < 16) ? (size_t)(bs * 16 + t)
                                : (size_t)(16384 + b * 16 + (t - 16));
    const _Float16* qp = qkv + row * W3 + h * HD;

    float ccA[8], ssA[8], ccB[8], ssB[8];
#pragma unroll
    for (int j = 0; j < 8; ++j) {
        float aA = (float)t * ropefreq(8 * half + j);
        float aB = (float)t * ropefreq(16 + 8 * half + j);
        __sincosf(aA, &ssA[j], &ccA[j]);
        __sincosf(aB, &ssB[j], &ccB[j]);
    }

    // ---- stage V ----
    h8 v0 = *(const h8*)(qp + 2 * DD + 32 * half);
    h8 v1 = *(const h8*)(qp + 2 * DD + 32 * half + 8);
    h8 v2 = *(const h8*)(qp + 2 * DD + 32 * half + 16);
    h8 v3 = *(const h8*)(qp + 2 * DD + 32 * half + 24);
    *(h8*)&vl[t * 72 + 32 * half +  0] = v0;
    *(h8*)&vl[t * 72 + 32 * half +  8] = v1;
    *(h8*)&vl[t * 72 + 32 * half + 16] = v2;
    *(h8*)&vl[t * 72 + 32 * half + 24] = v3;

    // ---- load Q,K chunks + in-register RoPE ----
    h8 q0 = *(const h8*)(qp + 8 * half);
    h8 q1 = *(const h8*)(qp + 8 * half + 16);
    h8 q2 = *(const h8*)(qp + 8 * half + 32);
    h8 q3 = *(const h8*)(qp + 8 * half + 48);
    h8 k0 = *(const h8*)(qp + DD + 8 * half);
    h8 k1 = *(const h8*)(qp + DD + 8 * half + 16);
    h8 k2 = *(const h8*)(qp + DD + 8 * half + 32);
    h8 k3 = *(const h8*)(qp + DD + 8 * half + 48);

    h8 qf0, qf1, qf2, qf3, kf0, kf1, kf2, kf3;
#pragma unroll
    for (int j = 0; j < 8; ++j) {
        float x1 = (float)q0[j], x2 = (float)q2[j];
        qf0[j] = (_Float16)(0.125f * (x1 * ccA[j] - x2 * ssA[j]));
        qf2[j] = (_Float16)(0.125f * (x2 * ccA[j] + x1 * ssA[j]));
        x1 = (float)q1[j]; x2 = (float)q3[j];
        qf1[j] = (_Float16)(0.125f * (x1 * ccB[j] - x2 * ssB[j]));
        qf3[j] = (_Float16)(0.125f * (x2 * ccB[j] + x1 * ssB[j]));
        x1 = (float)k0[j]; x2 = (float)k2[j];
        kf0[j] = (_Float16)(x1 * ccA[j] - x2 * ssA[j]);
        kf2[j] = (_Float16)(x2 * ccA[j] + x1 * ssA[j]);
        x1 = (float)k1[j]; x2 = (float)k3[j];
        kf1[j] = (_Float16)(x1 * ccB[j] - x2 * ssB[j]);
        kf3[j] = (_Float16)(x2 * ccB[j] + x1 * ssB[j]);
    }

    // ---- scores ----
    f16v s4 = {};
    s4 = __builtin_amdgcn_mfma_f32_32x32x16_f16(qf0, kf0, s4, 0, 0, 0);
    s4 = __builtin_amdgcn_mfma_f32_32x32x16_f16(qf1, kf1, s4, 0, 0, 0);
    s4 = __builtin_amdgcn_mfma_f32_32x32x16_f16(qf2, kf2, s4, 0, 0, 0);
    s4 = __builtin_amdgcn_mfma_f32_32x32x16_f16(qf3, kf3, s4, 0, 0, 0);

    // ---- softmax per row ----
#pragma unroll
    for (int r = 0; r < 16; ++r) {
        float m = s4[r];
#pragma unroll
        for (int mask = 1; mask <= 16; mask <<= 1)
            m = fmaxf(m, __shfl_xor(m, mask));
        float e = __expf(s4[r] - m);
        float sm = e;
#pragma unroll
        for (int mask = 1; mask <= 16; mask <<= 1)
            sm += __shfl_xor(sm, mask);
        float p = e / sm;
        int rr = (r & 3) + 8 * (r >> 2) + 4 * half;
        pl[rr * 40 + t] = (_Float16)p;
    }

    // ---- O = P V ----
    f16v o_acc[2];
#pragma unroll
    for (int n0 = 0; n0 < 2; ++n0) {
        f16v o = {};
#pragma unroll
        for (int kk = 0; kk < 2; ++kk) {
            h8 pf = *(const h8*)&pl[t * 40 + kk * 16 + half * 8];
            h8 vf;
#pragma unroll
            for (int jj = 0; jj < 8; ++jj)
                vf[jj] = vl[(kk * 16 + half * 8 + jj) * 72 + n0 * 32 + t];
            o = __builtin_amdgcn_mfma_f32_32x32x16_f16(pf, vf, o, 0, 0, 0);
        }
        o_acc[n0] = o;
    }

    // ---- V tile dead; stage O into it (wave-synchronous) ----
#pragma unroll
    for (int n0 = 0; n0 < 2; ++n0)
#pragma unroll
        for (int r = 0; r < 16; ++r) {
            int i = (r & 3) + 8 * (r >> 2) + 4 * half;
            vl[i * 72 + n0 * 32 + t] = (_Float16)o_acc[n0][r];
        }

    // ---- coalesced write-back ----
#pragma unroll
    for (int rr = 0; rr < 4; ++rr) {
        int i = rr * 8 + (lane >> 3);
        int c = (lane & 7) * 8;
        h8 val = *(const h8*)&vl[i * 72 + c];
        if (rr < 2)
            *(h8*)&attnv[(size_t)(bs * 16 + i) * DD + h * HD + c] = val;
        else
            *(h8*)&attna[(((size_t)b * 16 + (i - 16)) * SS + s) * DD + h * HD + c] = val;
    }
}

// ---------------------------------------------------------------------------
// reduce_a: 64 blocks, one per (b,t) a-row. Mean over 256 contiguous rows of
// attna -> fp16 abar written as rows 16384.. of the proj A matrix (attnv).
// Thread (sg=tid>>6, cl=tid&63) sums 64 rows for col-chunk cl (h8);
// 4-way cross-sg combine via LDS.
// ---------------------------------------------------------------------------
__global__ __launch_bounds__(256)
void reduce_a_kernel(const _Float16* __restrict__ attna, _Float16* __restrict__ abar) {
    __shared__ float red[4][DD];          // 8 KB
    const int r = blockIdx.x;             // 0..63  (b*16 + t)
    const int tid = threadIdx.x;
    const int sg = tid >> 6, cl = tid & 63;

    float acc[8] = {};
    const _Float16* base = attna + ((size_t)r * SS + sg * 64) * DD + cl * 8;
#pragma unroll 4
    for (int i = 0; i < 64; ++i) {
        h8 v = *(const h8*)(base + (size_t)i * DD);
#pragma unroll
        for (int j = 0; j < 8; ++j) acc[j] += (float)v[j];
    }
#pragma unroll
    for (int j = 0; j < 8; ++j) red[sg][cl * 8 + j] = acc[j];
    __syncthreads();

    // 256 threads -> 512 cols, 2 each
    int c = tid * 2;
    float s0 = red[0][c] + red[1][c] + red[2][c] + red[3][c];
    float s1 = red[0][c + 1] + red[1][c + 1] + red[2][c + 1] + red[3][c + 1];
    h2 o = { (_Float16)(s0 * (1.0f / SS)), (_Float16)(s1 * (1.0f / SS)) };
    *(h2*)&abar[(size_t)r * DD + c] = o;
}

// ---------------------------------------------------------------------------
// MFMA GEMM 2: out[16512][512] = Av[16512][512] @ Wp + bias, where Av rows
// 0..16383 = attnv (v-rows), 16384..16447 = abar (a-row means), rest pad.
// 128x128 tiles, BK=64 XOR swizzle, 1-D grid 129*4=516 (ONE dispatch round
// at 3 blk/CU), tn-fastest. Epilogue scatters v-rows -> vp/vf, a-rows ->
// ap/af; pad rows discarded.
// ---------------------------------------------------------------------------
__global__ __launch_bounds__(256, 3)
void proj_kernel(const _Float16* __restrict__ A, const _Float16* __restrict__ Bt,
                 const float* __restrict__ bp, float* __restrict__ out) {
    __shared__ __align__(16) _Float16 As[128 * 64];   // 16 KB
    __shared__ __align__(16) _Float16 Bs[128 * 64];   // 16 KB
    const int tid = threadIdx.x, lane = tid & 63, wave = tid >> 6;
    const int bid = blockIdx.x;
    const int tm = bid >> 2, tn = bid & 3;
    const int m_base = (wave >> 1) * 64, n_base = (wave & 1) * 64;
    const int quad = lane >> 4, l16 = lane & 15;

    f4 acc[4][4] = {};

    int srow[4], soff[4];
#pragma unroll
    for (int p = 0; p < 4; ++p) {
        int ci = p * 256 + tid;
        int r = ci >> 3, sl = ci & 7;
        srow[p] = r;
        soff[p] = (sl ^ (r & 7)) * 8;
    }

    for (int k0 = 0; k0 < 512; k0 += 64) {
#pragma unroll
        for (int p = 0; p < 4; ++p) {
            int ci = p * 256 + tid;
            async16(A  + (size_t)(tm * 128 + srow[p]) * 512 + k0 + soff[p],
                    &As[ci * 8]);
            async16(Bt + (size_t)(tn * 128 + srow[p]) * 512 + k0 + soff[p],
                    &Bs[ci * 8]);
        }
        __syncthreads();

#pragma unroll
        for (int kk = 0; kk < 2; ++kk) {
            h8 af[4], bf[4];
#pragma unroll
            for (int mi = 0; mi < 4; ++mi) {
                int m = m_base + mi * 16 + l16;
                int sl = (kk * 4 + quad) ^ (m & 7);
                af[mi] = *(const h8*)&As[m * 64 + sl * 8];
            }
#pragma unroll
            for (int ni = 0; ni < 4; ++ni) {
                int n = n_base + ni * 16 + l16;
                int sl = (kk * 4 + quad) ^ (n & 7);
                bf[ni] = *(const h8*)&Bs[n * 64 + sl * 8];
            }
#pragma unroll
            for (int mi = 0; mi < 4; ++mi)
#pragma unroll
                for (int ni = 0; ni < 4; ++ni)
                    acc[mi][ni] = __builtin_amdgcn_mfma_f32_16x16x32_f16(
                        af[mi], bf[ni], acc[mi][ni], 0, 0, 0);
        }
        __syncthreads();
    }

#pragma unroll
    for (int mi = 0; mi < 4; ++mi)
#pragma unroll
        for (int ni = 0; ni < 4; ++ni) {
            int row0 = tm * 128 + m_base + mi * 16 + quad * 4;
            int col  = tn * 128 + n_base + ni * 16 + l16;
            float bias = bp[col];
#pragma unroll
            for (int r = 0; r < 4; ++r) {
                int row = row0 + r;
                float val = acc[mi][ni][r] + bias;
                if (row < 16384) {
                    int bsq = row >> 4, t = row & 15;
                    int b = bsq >> 8, s = bsq & 255;
                    size_t off = (t < 8)
                        ? (VP_BASE + (size_t)((b * 8 + t) * SS + s) * DD + col)
                        : (VF_BASE + (size_t)((b * 8 + t - 8) * SS + s) * DD + col);
                    out[off] = val;
                } else if (row < 16448) {
                    int idx = row - 16384;
                    int b = idx >> 4, t2 = idx & 15;
                    size_t off = (t2 < 8)
                        ? (AP_BASE + (size_t)(b * 8 + t2) * DD + col)
                        : (AF_BASE + (size_t)(b * 8 + (t2 - 8)) * DD + col);
                    out[off] = val;
                }
            }
        }
}

// ---------------------------------------------------------------------------
extern "C" void kernel_launch(void* const* d_in, const int* in_sizes, int n_in,
                              void* d_out, int out_size, void* d_ws, size_t ws_size,
                              hipStream_t stream) {
    const float* v_p  = (const float*)d_in[0];
    const float* v_f  = (const float*)d_in[1];
    const float* a_p  = (const float*)d_in[2];
    const float* a_f  = (const float*)d_in[3];
    const float* Wqkv = (const float*)d_in[4];
    const float* Wp   = (const float*)d_in[5];
    const float* bp   = (const float*)d_in[6];
    float* out = (float*)d_out;

    // Workspace layout (~86.8 MB). attna ALIASES tok (tok dead after
    // gemm_qkv; attna written by attn5 later on stream).
    char* w = (char*)d_ws;
    _Float16* tok   = (_Float16*)w;  w += (size_t)MPAD * DD * 2;    // 16.9 MB
    _Float16* qkv   = (_Float16*)w;  w += (size_t)MPAD * W3 * 2;    // 50.7 MB
    _Float16* attnv = (_Float16*)w;  w += (size_t)MPAD * DD * 2;    // 16.9 MB (incl. abar rows)
    _Float16* Wt    = (_Float16*)w;  w += (size_t)W3 * DD * 2;      //  1.6 MB
    _Float16* Wpt   = (_Float16*)w;  w += (size_t)DD * DD * 2;      //  0.5 MB
    _Float16* attna = tok;                                          // alias
    _Float16* abar  = attnv + (size_t)16384 * DD;                   // rows 16384..

    conv_kernel<<<8480, 256, 0, stream>>>(v_p, v_f, a_p, a_f, Wqkv, Wp,
                                          tok, Wt, Wpt);
    gemm_qkv_kernel<<<129 * 12, 256, 0, stream>>>(tok, Wt, qkv);
    attn5_kernel<<<2048, 256, 0, stream>>>(qkv, attnv, attna);
    reduce_a_kernel<<<64, 256, 0, stream>>>(attna, abar);
    proj_kernel<<<129 * 4, 256, 0, stream>>>(attnv, Wpt, bp, out);
}